// Round 5
// baseline (38.219 us; speedup 1.0000x reference)
//
#include <hip/hip_runtime.h>

#define B_     8
#define L_     512
#define DIM_   256
#define INNER_ 512
#define M_ROWS (B_*L_)        // 4096

typedef __bf16 bf16x8 __attribute__((ext_vector_type(8)));
typedef float  fl4    __attribute__((ext_vector_type(4)));

__device__ __forceinline__ unsigned short f2bf(float f) {
    unsigned int u = __float_as_uint(f);
    u = (u + 0x7fffu + ((u >> 16) & 1u)) >> 16;   // RNE
    return (unsigned short)u;
}
__device__ __forceinline__ ushort4 f4bf4(float4 v) {
    union { __bf16 h[4]; ushort4 u; } r;
    r.h[0] = (__bf16)v.x; r.h[1] = (__bf16)v.y;
    r.h[2] = (__bf16)v.z; r.h[3] = (__bf16)v.w;
    return r.u;
}

// ---------------------------------------------------------------- K0: convert x, Win, Wout -> bf16
__global__ __launch_bounds__(256) void convert_all(
    const float* __restrict__ x, const float* __restrict__ win,
    const float* __restrict__ wout,
    unsigned short* __restrict__ xb, unsigned short* __restrict__ winb,
    unsigned short* __restrict__ woutb)
{
    const int NX4 = (M_ROWS*DIM_) / 4;        // 262144
    const int NW4 = (2*INNER_*DIM_) / 4;      // 65536
    const int NO4 = (DIM_*INNER_) / 4;        // 32768
    int i4 = blockIdx.x * blockDim.x + threadIdx.x;  // grid covers exactly NX4+NW4+NO4
    const float* src; unsigned short* dst; int off;
    if (i4 < NX4)             { src = x;    dst = xb;    off = i4; }
    else if (i4 < NX4+NW4)    { src = win;  dst = winb;  off = i4 - NX4; }
    else                      { src = wout; dst = woutb; off = i4 - NX4 - NW4; }
    float4 v = *(const float4*)&src[(size_t)off*4];
    *(ushort4*)&dst[(size_t)off*4] = f4bf4(v);
}

// ---------------------------------------------------------------- P1: gemm1 + conv + scan + gate
// Block = (batch b = blk&7  [XCD-local], channel group cg = blk>>3).
// Wave w owns rows w*64..w*64+63 (the l axis); 16 u-cols + 16 g-cols.
// GEMM fragments loaded DIRECTLY from global (no LDS, no K-loop barriers).
__global__ __launch_bounds__(512) void p1_fused(
    const unsigned short* __restrict__ xb, const unsigned short* __restrict__ winb,
    const float* __restrict__ convw, const float* __restrict__ sdecay,
    const float* __restrict__ sscale,
    unsigned short* __restrict__ yb)
{
    __shared__ __align__(16) char smem[72*1024];
    float* u_lds = (float*)smem;                  // [512][17] f32 = 34816 B
    float* g_lds = (float*)(smem + 34816);        // [512][17]
    float* carry = (float*)(smem + 69632);        // [32][16]

    const int tid  = threadIdx.x;
    const int wave = tid >> 6, lane = tid & 63;
    const int b  = blockIdx.x & 7;                // XCD id (blk % 8)
    const int cg = blockIdx.x >> 3;               // 0..31
    const int r15 = lane & 15, q = lane >> 4;

    // ---- GEMM: C[512][32] = x[b] . [Win_u rows ++ Win_g rows]^T
    {
        const size_t arow0 = ((size_t)(b*L_ + wave*64 + r15)) * DIM_;
        const size_t urow  = ((size_t)(cg*16 + r15)) * DIM_;
        const size_t grow  = ((size_t)(INNER_ + cg*16 + r15)) * DIM_;

        fl4 acc[4][2] = {};
        #pragma unroll
        for (int kt = 0; kt < DIM_; kt += 32) {
            const int ko = kt + q*8;
            const bf16x8 bu = *(const bf16x8*)&winb[urow + ko];
            const bf16x8 bg = *(const bf16x8*)&winb[grow + ko];
            #pragma unroll
            for (int m = 0; m < 4; ++m) {
                const bf16x8 a = *(const bf16x8*)&xb[arow0 + (size_t)m*16*DIM_ + ko];
                acc[m][0] = __builtin_amdgcn_mfma_f32_16x16x32_bf16(a, bu, acc[m][0], 0, 0, 0);
                acc[m][1] = __builtin_amdgcn_mfma_f32_16x16x32_bf16(a, bg, acc[m][1], 0, 0, 0);
            }
        }
        // dump accumulators to LDS: row l, col = channel-in-group (lane&15)
        #pragma unroll
        for (int m = 0; m < 4; ++m)
            #pragma unroll
            for (int r = 0; r < 4; ++r) {
                const int l = wave*64 + m*16 + q*4 + r;
                u_lds[l*17 + r15] = acc[m][0][r];
                g_lds[l*17 + r15] = acc[m][1][r];
            }
    }
    __syncthreads();

    // ---- conv(3) + linear scan + gate. thread = channel c2 x chunk j of 16 steps.
    {
        const int c2 = tid & 15;
        const int j  = tid >> 4;                  // 0..31
        const int c  = cg*16 + c2;                // global channel

        const float draw = 1.0f / (1.0f + __expf(-sdecay[c]));
        const float deff = fmaxf(draw, 1e-6f);
        const float ins  = (1.0f - draw) * sscale[c];
        const float w0 = convw[c*3+0], w1 = convw[c*3+1], w2 = convw[c*3+2];

        const int l0 = j*16;
        float um1 = (l0 >= 1) ? u_lds[(l0-1)*17 + c2] : 0.f;
        float um2 = (l0 >= 2) ? u_lds[(l0-2)*17 + c2] : 0.f;

        float sloc[16];
        float s = 0.f;
        #pragma unroll
        for (int i = 0; i < 16; ++i) {
            const float u = u_lds[(l0+i)*17 + c2];
            const float uc = fmaf(w2, u, fmaf(w1, um1, w0*um2));
            um2 = um1; um1 = u;
            s = fmaf(deff, s, ins*uc);
            sloc[i] = s;
        }
        carry[j*16 + c2] = s;
        __syncthreads();
        const float dp16 = __powf(deff, 16.0f);
        float s0 = 0.f;
        for (int i = 0; i < j; ++i) s0 = fmaf(s0, dp16, carry[i*16 + c2]);

        float pw = 1.0f;
        #pragma unroll
        for (int i = 0; i < 16; ++i) {
            pw *= deff;
            const float sv   = fmaf(s0, pw, sloc[i]);
            const float gate = 1.0f / (1.0f + __expf(-g_lds[(l0+i)*17 + c2]));
            yb[(size_t)(b*L_ + l0 + i)*INNER_ + c] = f2bf(sv * gate);
        }
    }
}

// ---------------------------------------------------------------- P3: gemm2 + fused RMSNorm
// Block = 16 rows x all 256 cols. Direct-load fragments, no LDS staging.
// Row mapping mirrors p1's XCD layout: b = blk&7 so yb reads are L2-local.
__global__ __launch_bounds__(512) void p3_gemm2(
    const unsigned short* __restrict__ yb,
    const unsigned short* __restrict__ woutb,
    const float* __restrict__ normw,
    float* __restrict__ out)
{
    __shared__ float ssp[16*8];
    const int tid  = threadIdx.x;
    const int wave = tid >> 6, lane = tid & 63;
    const int r15 = lane & 15, q = lane >> 4;
    const int row0 = (blockIdx.x & 7)*L_ + (blockIdx.x >> 3)*16;
    const int wc   = wave * 32;

    fl4 acc[2] = {};
    {
        const size_t abase = ((size_t)(row0 + r15)) * INNER_;
        const size_t bb0   = ((size_t)(wc + r15)) * INNER_;
        const size_t bb1   = ((size_t)(wc + 16 + r15)) * INNER_;
        #pragma unroll
        for (int kt = 0; kt < INNER_; kt += 32) {
            const int ko = kt + q*8;
            const bf16x8 a = *(const bf16x8*)&yb[abase + ko];
            acc[0] = __builtin_amdgcn_mfma_f32_16x16x32_bf16(
                         a, *(const bf16x8*)&woutb[bb0 + ko], acc[0], 0, 0, 0);
            acc[1] = __builtin_amdgcn_mfma_f32_16x16x32_bf16(
                         a, *(const bf16x8*)&woutb[bb1 + ko], acc[1], 0, 0, 0);
        }
    }

    float t[4];
    #pragma unroll
    for (int qq = 0; qq < 4; ++qq) {
        float s = 0.f;
        #pragma unroll
        for (int n = 0; n < 2; ++n) { const float v = acc[n][qq]; s = fmaf(v, v, s); }
        s += __shfl_xor(s, 1, 64); s += __shfl_xor(s, 2, 64);
        s += __shfl_xor(s, 4, 64); s += __shfl_xor(s, 8, 64);
        t[qq] = s;
    }
    if (r15 == 0) {
        #pragma unroll
        for (int qq = 0; qq < 4; ++qq)
            ssp[(q*4 + qq)*8 + wave] = t[qq];
    }
    __syncthreads();
    #pragma unroll
    for (int qq = 0; qq < 4; ++qq) {
        const int rl = q*4 + qq;
        float ss = 0.f;
        #pragma unroll
        for (int w = 0; w < 8; ++w) ss += ssp[rl*8 + w];
        const float rf = rsqrtf(ss * (1.0f/DIM_) + 1e-6f);
        #pragma unroll
        for (int n = 0; n < 2; ++n) {
            const int col = wc + n*16 + r15;
            out[(size_t)(row0 + rl)*DIM_ + col] = acc[n][qq] * rf * normw[col];
        }
    }
}

// ---------------------------------------------------------------- launch
extern "C" void kernel_launch(void* const* d_in, const int* in_sizes, int n_in,
                              void* d_out, int out_size, void* d_ws, size_t ws_size,
                              hipStream_t stream)
{
    const float* x      = (const float*)d_in[0];
    const float* Win    = (const float*)d_in[1];
    const float* convw  = (const float*)d_in[2];
    const float* sdecay = (const float*)d_in[3];
    const float* sscale = (const float*)d_in[4];
    const float* Wout   = (const float*)d_in[5];
    const float* normw  = (const float*)d_in[6];
    float* out = (float*)d_out;

    char* ws = (char*)d_ws;
    unsigned short* xb    = (unsigned short*)(ws);                          // 2 MB
    unsigned short* winb  = (unsigned short*)(ws + (2u<<20));               // 0.5 MB
    unsigned short* woutb = (unsigned short*)(ws + (2u<<20) + (512u<<10));  // 0.25 MB
    unsigned short* yb    = (unsigned short*)(ws + (3u<<20));               // 4 MB

    convert_all<<<1408, 256, 0, stream>>>(x, Win, Wout, xb, winb, woutb);
    p1_fused<<<256, 512, 0, stream>>>(xb, winb, convw, sdecay, sscale, yb);
    p3_gemm2<<<256, 512, 0, stream>>>(yb, woutb, normw, out);
}